// Round 18
// baseline (305.399 us; speedup 1.0000x reference)
//
#include <hip/hip_runtime.h>

#define DEV __device__ __forceinline__

using f32x4 = __attribute__((ext_vector_type(4))) float;
using f16x8 = __attribute__((ext_vector_type(8))) _Float16;
using f16x4 = __attribute__((ext_vector_type(4))) _Float16;

constexpr int Bc = 8, Tc = 2048, Ec = 1024, Hc = 1024;
constexpr int Mc = Bc * Tc;    // 16384 total rows
constexpr int SLOT = 256 * 32; // elements per 16KB slice

DEV f32x4 mfma16(f16x8 a, f16x8 b, f32x4 c) {
    return __builtin_amdgcn_mfma_f32_16x16x32_f16(a, b, c, 0, 0, 0);
}
DEV unsigned short f16bits(float f) { return __builtin_bit_cast(unsigned short, (_Float16)f); }
DEV float f16val(unsigned short u) { return (float)__builtin_bit_cast(_Float16, u); }

// async global->LDS, 16B per lane. LDS dest must be wave-uniform base; HW adds lane*16.
DEV void gload16(const _Float16* g, _Float16* l) {
    __builtin_amdgcn_global_load_lds(
        (const __attribute__((address_space(1))) unsigned int*)g,
        (__attribute__((address_space(3))) unsigned int*)l, 16, 0, 0);
}

// Paired-row swizzled LDS slice layout (256x32 f16 = 16KB):
// LDS row r (128B) holds tile-rows {2r, 2r+1}; the 8 16B slots within row r
// are XOR-permuted by (r&7).  Verified 0 bank conflicts (rounds 5-17).
DEV int swz_off(int R, int lk) {
    return ((R >> 1) << 6) + ((((((R & 1) << 2) | lk) ^ ((R >> 1) & 7))) << 3);
}

// ---------------------------------------------------------------------------
// k_prep: merged prep_x (blocks [0,16384): f32 x -> f16), prep_w (blocks
// [16384,19456): transpose W -> Wall f16), and zero-init of the PV atomic
// region (blocks [19456,27648): out rows q in [1024,2048) for all batches —
// the K-split PV halves atomicAdd into these).
// ---------------------------------------------------------------------------
__global__ __launch_bounds__(256) void k_prep(const float* __restrict__ x,
                                              const float* __restrict__ wq,
                                              const float* __restrict__ wk,
                                              const float* __restrict__ wv,
                                              _Float16* __restrict__ xf,
                                              _Float16* __restrict__ wall,
                                              float* __restrict__ out) {
    __shared__ float tile[32][33];
    const int i = blockIdx.x;
    if (i < 16384) {
        const int idx = (i * 256 + threadIdx.x) * 4;  // covers Mc*Ec exactly
        f32x4 v = *reinterpret_cast<const f32x4*>(x + idx);
        f16x4 h;
#pragma unroll
        for (int j = 0; j < 4; j++) h[j] = (_Float16)v[j];
        *reinterpret_cast<f16x4*>(xf + idx) = h;
    } else if (i < 19456) {
        const int j = i - 16384;
        const int z = j >> 10;          // 0..2
        const int rem = j & 1023;
        const int n0 = (rem & 31) * 32, e0 = (rem >> 5) * 32;
        const float* src = (z == 0) ? wq : (z == 1) ? wk : wv;
        _Float16* dh = wall + (size_t)z * 1024 * Ec;
        const int tx = threadIdx.x & 31, ty = threadIdx.x >> 5;  // 32 x 8
#pragma unroll
        for (int jj = 0; jj < 32; jj += 8)
            tile[ty + jj][tx] = src[(size_t)(e0 + ty + jj) * Hc + n0 + tx];
        __syncthreads();
#pragma unroll
        for (int jj = 0; jj < 32; jj += 8)
            dh[(size_t)(n0 + ty + jj) * Ec + e0 + tx] = (_Float16)tile[tx][ty + jj];
    } else {
        // zero out rows q in [1024,2048) of every batch (8M floats total)
        const size_t j = ((size_t)(i - 19456) * 256 + threadIdx.x) * 4;
        const size_t b = j >> 20, off = j & 1048575;
        f32x4 zz = {0.f, 0.f, 0.f, 0.f};
        *reinterpret_cast<f32x4*>(out + b * 2097152 + 1048576 + off) = zz;
    }
}

// ---------------------------------------------------------------------------
// gemm_body: round-13 schedule (best measured).  256x256 tile, 8 waves
// (2x4, each 128x64), 512 threads, BK=32 slots over K-tile range
// [kt0, kt0+nkt), ring-3 LDS (96 KiB), ONE barrier per slot:
//   { 12 ds_read (bfr then af); stage(P+2) -> slot (P+2)%3 (4 gloads);
//     setprio(1); 32 MFMA; setprio(0); vmcnt(4); s_barrier }
// EPI: 0 = f16 out, N=2048: Q (gn<1024) / K (gn>=1024)
//      1 = f16 transposed store Vt[b][n][t]
//      2 = f16 causal energy * 1/sqrt(dk)
//      3 = f32 row-major (PV); atom!=0 -> atomicAdd (K-split halves)
// ---------------------------------------------------------------------------
template <int EPI>
DEV void gemm_body(int bx, int by, int z,
                   const _Float16* __restrict__ Ah, const _Float16* __restrict__ Bh,
                   void* __restrict__ out0, void* __restrict__ out2,
                   const int* __restrict__ dkp,
                   int lda, int ldb, size_t aBS, size_t bBS, size_t oBS,
                   int kt0, int nkt, int atom,
                   _Float16* sAb, _Float16* sBb) {
    Ah += (size_t)z * aBS;
    Bh += (size_t)z * bBS;

    const float scale = (EPI == 2) ? (1.0f / sqrtf((float)*dkp)) : 1.0f;

    const int tid = threadIdx.x;
    const int wave = tid >> 6, lane = tid & 63;
    const int lr = lane & 15, lk = lane >> 4;
    const int wm = wave >> 2, wn = wave & 3;  // 2 x 4 wave grid
    const int m0 = by * 256, n0 = bx * 256;

    // staging constants (inverse-swizzled global source, linear LDS dest):
    const int so = (lane & 7) ^ (lane >> 3);
    const int strow = 2 * (lane >> 3) + (so >> 2);
    const int stcol = (so & 3) * 8;
    const size_t aoff0 = (size_t)(m0 + (wave * 2 + 0) * 16 + strow) * lda + stcol;
    const size_t aoff1 = (size_t)(m0 + (wave * 2 + 1) * 16 + strow) * lda + stcol;
    const size_t boff0 = (size_t)(n0 + (wave * 2 + 0) * 16 + strow) * ldb + stcol;
    const size_t boff1 = (size_t)(n0 + (wave * 2 + 1) * 16 + strow) * ldb + stcol;
    const int ld0 = (wave * 2 + 0) * 512, ld1 = (wave * 2 + 1) * 512;

    auto stage = [&](int sv, int slot) {
        const int kk = sv * 32;
        _Float16* dA = sAb + slot * SLOT;
        _Float16* dB = sBb + slot * SLOT;
        gload16(Ah + aoff0 + kk, dA + ld0);
        gload16(Ah + aoff1 + kk, dA + ld1);
        gload16(Bh + boff0 + kk, dB + ld0);
        gload16(Bh + boff1 + kk, dB + ld1);
    };

    f32x4 acc[8][4] = {};

    // prologue: slots kt0 and kt0+1 in flight; gate slot 0 (allow 4 in flight)
    stage(kt0, 0);
    stage(kt0 + 1, 1);
    asm volatile("s_waitcnt vmcnt(4)" ::: "memory");
    __builtin_amdgcn_s_barrier();

    int rP = 0;  // i % 3
    for (int i = 0; i < nkt; ++i) {
        const _Float16* cA = sAb + rP * SLOT;
        const _Float16* cB = sBb + rP * SLOT;
        f16x8 af[8], bfr[4];

        // B frags first so the first MFMA's operands arrive earliest
#pragma unroll
        for (int nj = 0; nj < 4; nj++)
            bfr[nj] = *reinterpret_cast<const f16x8*>(
                &cB[swz_off(wn * 64 + nj * 16 + lr, lk)]);
#pragma unroll
        for (int mi = 0; mi < 8; mi++)
            af[mi] = *reinterpret_cast<const f16x8*>(
                &cA[swz_off(wm * 128 + mi * 16 + lr, lk)]);

        int rs = rP + 2; if (rs >= 3) rs -= 3;
        if (i + 2 < nkt) stage(kt0 + i + 2, rs);

        __builtin_amdgcn_s_setprio(1);
#pragma unroll
        for (int mi = 0; mi < 8; mi++)
#pragma unroll
            for (int nj = 0; nj < 4; nj++)
                acc[mi][nj] = mfma16(af[mi], bfr[nj], acc[mi][nj]);
        __builtin_amdgcn_s_setprio(0);

        // slot-exit gate: stage(i+1) must be complete (counted; never 0 in
        // steady state).  Skip entirely on the last slot.
        if (i + 2 < nkt) {
            asm volatile("s_waitcnt vmcnt(4)" ::: "memory");
            __builtin_amdgcn_s_barrier();
        } else if (i + 1 < nkt) {
            asm volatile("s_waitcnt vmcnt(0)" ::: "memory");
            __builtin_amdgcn_s_barrier();
        }
        if (++rP == 3) rP = 0;
    }

#pragma unroll
    for (int mi = 0; mi < 8; mi++)
#pragma unroll
        for (int nj = 0; nj < 4; nj++) {
            const int gn = n0 + wn * 64 + nj * 16 + lr;
            if (EPI == 1) {
                const int gm0 = m0 + wm * 128 + mi * 16 + lk * 4;
                const int bb = gm0 >> 11, t = gm0 & (Tc - 1);
                f16x4 pk;
#pragma unroll
                for (int r = 0; r < 4; r++) pk[r] = (_Float16)acc[mi][nj][r];
                *reinterpret_cast<f16x4*>(
                    &((_Float16*)out0)[((size_t)(bb * Hc + gn)) * Tc + t]) = pk;
            } else if (EPI == 0) {
                _Float16* od = (gn < 1024) ? (_Float16*)out0 : (_Float16*)out2;
                const int cc = gn & 1023;
#pragma unroll
                for (int r = 0; r < 4; r++) {
                    const int gm = m0 + wm * 128 + mi * 16 + lk * 4 + r;
                    od[(size_t)gm * Hc + cc] = (_Float16)acc[mi][nj][r];
                }
            } else {
#pragma unroll
                for (int r = 0; r < 4; r++) {
                    const int gm = m0 + wm * 128 + mi * 16 + lk * 4 + r;
                    const float v = acc[mi][nj][r];
                    if (EPI == 2) {
                        const float e = (gn > gm) ? -INFINITY : v * scale;
                        ((unsigned short*)out0)[(size_t)z * oBS + (size_t)gm * Tc + gn] =
                            f16bits(e);
                    } else {
                        float* op = (float*)out0 + (size_t)z * oBS + (size_t)gm * Hc + gn;
                        if (atom) atomicAdd(op, v);
                        else *op = v;
                    }
                }
            }
        }
}

// ---------------------------------------------------------------------------
// k_qkv: QK-projection (512 blocks) + V-projection (256 blocks), 32 slots.
// 768 blocks = exactly 3 rounds on 256 CUs (optimal packing).
// launch_bounds(512,2): do NOT tighten — (512,4) spilled acc to scratch
// (round 8: 5.8 GB traffic, 9x slowdown).
// ---------------------------------------------------------------------------
__global__ __launch_bounds__(512, 2) void k_qkv(
        const _Float16* __restrict__ Xf, const _Float16* __restrict__ Wall,
        _Float16* __restrict__ Qf, _Float16* __restrict__ Kf,
        _Float16* __restrict__ Vt, const int* __restrict__ dkp) {
    __shared__ _Float16 sA[3][SLOT];  // 48 KiB
    __shared__ _Float16 sB[3][SLOT];  // 48 KiB
    const int i = blockIdx.x;
    if (i < 512) {
        // QK proj: bijective XCD chunking over the (8 x 64) tile grid
        const int w = (i & 7) * 64 + (i >> 3);
        const int by = w >> 3, bx = w & 7;
        gemm_body<0>(bx, by, 0, Xf, Wall, Qf, Kf, dkp,
                     Ec, Ec, 0, 0, 0, 0, 32, 0, sA[0], sB[0]);
    } else {
        const int j = i - 512;  // V proj: (4 x 64) tile grid
        gemm_body<1>(j & 3, j >> 2, 0, Xf, Wall + (size_t)2048 * Ec,
                     Vt, nullptr, dkp, Ec, Ec, 0, 0, 0, 0, 32, 0, sA[0], sB[0]);
    }
}

// ---------------------------------------------------------------------------
// k_energy: 288 causal tiles (36 per batch), single-term f16, 32 slots.
// ---------------------------------------------------------------------------
__global__ __launch_bounds__(512, 2) void k_energy(
        const _Float16* __restrict__ Qf, const _Float16* __restrict__ Kf,
        unsigned short* __restrict__ S, const int* __restrict__ dkp) {
    __shared__ _Float16 sA[3][SLOT];
    __shared__ _Float16 sB[3][SLOT];
    const int i = blockIdx.x;
    const int b = i / 36;
    int t = i - b * 36;
    int by = 0;
    while (t >= by + 1) { t -= by + 1; by++; }  // triangle decode: bx=t <= by
    gemm_body<2>(t, by, b, Qf, Kf, S, nullptr, dkp,
                 Hc, Hc, (size_t)Tc * Hc, (size_t)Tc * Hc, (size_t)Tc * Tc,
                 0, 32, 0, sA[0], sB[0]);
}

// ---------------------------------------------------------------------------
// k_pv: 384 blocks, LPT-ordered (descending slot count) so HW FIFO dispatch
// approximates balanced scheduling:
//   seg0 [  0, 64): by7 K-halves, 32 slots, atomic
//   seg1 [ 64, 96): by3 normal,   32 slots
//   seg2 [ 96,160): by6 K-halves, 28 slots, atomic
//   seg3 [160,224): by5 K-halves, 24 slots, atomic
//   seg4 [224,256): by2 normal,   24 slots
//   seg5 [256,320): by4 K-halves, 20 slots, atomic
//   seg6 [320,352): by1 normal,   16 slots
//   seg7 [352,384): by0 normal,    8 slots
// Halves atomicAdd f32 into the zero-initialized q>=1024 region (two
// commutative f32 adds per element — deterministic).
// ---------------------------------------------------------------------------
__global__ __launch_bounds__(512, 2) void k_pv(
        const _Float16* __restrict__ S, const _Float16* __restrict__ Vt,
        float* __restrict__ out, const int* __restrict__ dkp) {
    __shared__ _Float16 sA[3][SLOT];
    __shared__ _Float16 sB[3][SLOT];
    const int i = blockIdx.x;
    int by, ktn, kt0 = 0, atom = 0, r;
    if (i < 64)        { by = 7; ktn = 32; r = i;        atom = 1; kt0 = (r & 1) * 32; r >>= 1; }
    else if (i < 96)   { by = 3; ktn = 32; r = i - 64; }
    else if (i < 160)  { by = 6; ktn = 28; r = i - 96;   atom = 1; kt0 = (r & 1) * 28; r >>= 1; }
    else if (i < 224)  { by = 5; ktn = 24; r = i - 160;  atom = 1; kt0 = (r & 1) * 24; r >>= 1; }
    else if (i < 256)  { by = 2; ktn = 24; r = i - 224; }
    else if (i < 320)  { by = 4; ktn = 20; r = i - 256;  atom = 1; kt0 = (r & 1) * 20; r >>= 1; }
    else if (i < 352)  { by = 1; ktn = 16; r = i - 320; }
    else               { by = 0; ktn = 8;  r = i - 352; }
    const int bx = r & 3, b = r >> 2;
    gemm_body<3>(bx, by, b, S, Vt, out, nullptr, dkp,
                 Tc, Tc, (size_t)Tc * Tc, (size_t)Hc * Tc, (size_t)Tc * Hc,
                 kt0, ktn, atom, sA[0], sB[0]);
}

// ---------------------------------------------------------------------------
// softmax_w: ONE WAVE per row (4 rows per 256-thread block) — pure __shfl
// reductions, no LDS, no barriers.  f16 logits in, f16 P out (in place).
// Chunks beyond the tile-aligned causal extent skip load/store entirely.
// ---------------------------------------------------------------------------
__global__ __launch_bounds__(256) void softmax_w(unsigned short* __restrict__ S) {
    const int rid = blockIdx.x * 4 + (threadIdx.x >> 6);  // b*Tc + q
    const int lane = threadIdx.x & 63;
    const int q = rid & (Tc - 1);
    const int limit = ((q >> 8) + 1) << 8;  // tile-aligned causal extent
    unsigned short* row = S + (size_t)rid * Tc;

    float v[4][8];
    bool act[4];
#pragma unroll
    for (int c = 0; c < 4; c++) {
        const int c0 = c * 512 + lane * 8;
        act[c] = c0 < limit;
        if (act[c]) {
            uint4 raw = *reinterpret_cast<const uint4*>(row + c0);
            unsigned u[4] = {raw.x, raw.y, raw.z, raw.w};
#pragma unroll
            for (int p = 0; p < 4; p++) {
                v[c][2 * p]     = f16val((unsigned short)(u[p] & 0xFFFFu));
                v[c][2 * p + 1] = f16val((unsigned short)(u[p] >> 16));
            }
#pragma unroll
            for (int i = 0; i < 8; i++)
                if (c0 + i > q) v[c][i] = -INFINITY;
        } else {
#pragma unroll
            for (int i = 0; i < 8; i++) v[c][i] = -INFINITY;
        }
    }

    float m = -INFINITY;
#pragma unroll
    for (int c = 0; c < 4; c++)
#pragma unroll
        for (int i = 0; i < 8; i++) m = fmaxf(m, v[c][i]);
#pragma unroll
    for (int off = 1; off < 64; off <<= 1) m = fmaxf(m, __shfl_xor(m, off));

    float s = 0.f;
#pragma unroll
    for (int c = 0; c < 4; c++)
#pragma unroll
        for (int i = 0; i < 8; i++) {
            v[c][i] = __expf(v[c][i] - m);  // exp(-inf)=0
            s += v[c][i];
        }
#pragma unroll
    for (int off = 1; off < 64; off <<= 1) s += __shfl_xor(s, off);
    const float inv = 1.0f / s;

#pragma unroll
    for (int c = 0; c < 4; c++) {
        if (!act[c]) continue;
        const int c0 = c * 512 + lane * 8;
        unsigned o[4];
#pragma unroll
        for (int p = 0; p < 4; p++) {
            unsigned short a = f16bits(v[c][2 * p] * inv);
            unsigned short bb = f16bits(v[c][2 * p + 1] * inv);
            o[p] = (unsigned)a | ((unsigned)bb << 16);
        }
        uint4 w; w.x = o[0]; w.y = o[1]; w.z = o[2]; w.w = o[3];
        *reinterpret_cast<uint4*>(row + c0) = w;
    }
}

// ---------------------------------------------------------------------------
extern "C" void kernel_launch(void* const* d_in, const int* in_sizes, int n_in,
                              void* d_out, int out_size, void* d_ws, size_t ws_size,
                              hipStream_t stream) {
    const float* x  = (const float*)d_in[0];
    const float* Wq = (const float*)d_in[1];
    const float* Wk = (const float*)d_in[2];
    const float* Wv = (const float*)d_in[3];
    const int*   dk = (const int*)d_in[4];
    float* out = (float*)d_out;
    char* ws = (char*)d_ws;

    const size_t SZ_XE = (size_t)Mc * Ec * 2;  // 32 MiB (f16 [16384][1024])
    const size_t SZ_W  = (size_t)Ec * Hc * 2;  // 2 MiB

    // Layout: persistent buffers first, prep buffers last so S can alias them.
    size_t o = 0;
    auto nxt = [&](size_t bytes) { void* p = ws + o; o += bytes; return p; };
    _Float16* Qf   = (_Float16*)nxt(SZ_XE);
    _Float16* Kf   = (_Float16*)nxt(SZ_XE);
    _Float16* Vt   = (_Float16*)nxt(SZ_XE);
    _Float16* Xf   = (_Float16*)nxt(SZ_XE);
    _Float16* Wall = (_Float16*)nxt(3 * SZ_W);  // [3072][1024] = Wq|Wk|Wv, transposed
    // S: all-batch f16 [8][2048][2048] = 64 MiB, aliases Xf+Wall+beyond
    // (Xf and Wall are dead once k_qkv completes; k_energy is stream-ordered).
    unsigned short* S = (unsigned short*)Xf;
    (void)ws_size; (void)in_sizes; (void)n_in; (void)out_size;

    // merged prep: x->f16 (16384) + W transpose (3072) + out atomic-region
    // zero-init (8192)
    k_prep<<<27648, 256, 0, stream>>>(x, Wq, Wk, Wv, Xf, Wall, out);

    // Q, K, V projections: single-term f16, K=1024 (round-13 config)
    k_qkv<<<768, 512, 0, stream>>>(Xf, Wall, Qf, Kf, Vt, dk);

    // energy: 288 causal tiles, f16 logits (round-13 config)
    k_energy<<<288, 512, 0, stream>>>(Qf, Kf, (unsigned short*)S, dk);

    // softmax: one wave per row, 4 rows/block
    softmax_w<<<Bc * Tc / 4, 256, 0, stream>>>((unsigned short*)S);

    // PV: LPT-ordered 384 blocks; by>=4 K-split halves atomicAdd
    k_pv<<<384, 512, 0, stream>>>((const _Float16*)S, Vt, out, dk);
}

// Round 19
// 280.361 us; speedup vs baseline: 1.0893x; 1.0893x over previous
//
#include <hip/hip_runtime.h>

#define DEV __device__ __forceinline__

using f32x4 = __attribute__((ext_vector_type(4))) float;
using f16x8 = __attribute__((ext_vector_type(8))) _Float16;
using f16x4 = __attribute__((ext_vector_type(4))) _Float16;

constexpr int Bc = 8, Tc = 2048, Ec = 1024, Hc = 1024;
constexpr int Mc = Bc * Tc;    // 16384 total rows
constexpr int SLOT = 256 * 32; // elements per 16KB slice

DEV f32x4 mfma16(f16x8 a, f16x8 b, f32x4 c) {
    return __builtin_amdgcn_mfma_f32_16x16x32_f16(a, b, c, 0, 0, 0);
}
DEV unsigned short f16bits(float f) { return __builtin_bit_cast(unsigned short, (_Float16)f); }
DEV float f16val(unsigned short u) { return (float)__builtin_bit_cast(_Float16, u); }

// async global->LDS, 16B per lane. LDS dest must be wave-uniform base; HW adds lane*16.
DEV void gload16(const _Float16* g, _Float16* l) {
    __builtin_amdgcn_global_load_lds(
        (const __attribute__((address_space(1))) unsigned int*)g,
        (__attribute__((address_space(3))) unsigned int*)l, 16, 0, 0);
}

// Paired-row swizzled LDS slice layout (256x32 f16 = 16KB):
// LDS row r (128B) holds tile-rows {2r, 2r+1}; the 8 16B slots within row r
// are XOR-permuted by (r&7).  Verified 0 bank conflicts (rounds 5-18).
DEV int swz_off(int R, int lk) {
    return ((R >> 1) << 6) + ((((((R & 1) << 2) | lk) ^ ((R >> 1) & 7))) << 3);
}

// ---------------------------------------------------------------------------
// k_prep: merged prep_x (blocks [0,16384): f32 x -> f16) and prep_w
// (blocks [16384,19456): transpose W[e][n] -> Wall[n][e], f16).
// Wall[3072][1024]: rows [0,1024)=Wq, [1024,2048)=Wk, [2048,3072)=Wv.
// ---------------------------------------------------------------------------
__global__ __launch_bounds__(256) void k_prep(const float* __restrict__ x,
                                              const float* __restrict__ wq,
                                              const float* __restrict__ wk,
                                              const float* __restrict__ wv,
                                              _Float16* __restrict__ xf,
                                              _Float16* __restrict__ wall) {
    __shared__ float tile[32][33];
    const int i = blockIdx.x;
    if (i < 16384) {
        const int idx = (i * 256 + threadIdx.x) * 4;  // covers Mc*Ec exactly
        f32x4 v = *reinterpret_cast<const f32x4*>(x + idx);
        f16x4 h;
#pragma unroll
        for (int j = 0; j < 4; j++) h[j] = (_Float16)v[j];
        *reinterpret_cast<f16x4*>(xf + idx) = h;
    } else {
        const int j = i - 16384;
        const int z = j >> 10;          // 0..2
        const int rem = j & 1023;
        const int n0 = (rem & 31) * 32, e0 = (rem >> 5) * 32;
        const float* src = (z == 0) ? wq : (z == 1) ? wk : wv;
        _Float16* dh = wall + (size_t)z * 1024 * Ec;
        const int tx = threadIdx.x & 31, ty = threadIdx.x >> 5;  // 32 x 8
#pragma unroll
        for (int jj = 0; jj < 32; jj += 8)
            tile[ty + jj][tx] = src[(size_t)(e0 + ty + jj) * Hc + n0 + tx];
        __syncthreads();
#pragma unroll
        for (int jj = 0; jj < 32; jj += 8)
            dh[(size_t)(n0 + ty + jj) * Ec + e0 + tx] = (_Float16)tile[tx][ty + jj];
    }
}

// ---------------------------------------------------------------------------
// gemm_body: round-13 body VERBATIM (best measured: 110.7 us k_qkv, 280.6 us
// total).  256x256 tile, 8 waves (2x4, each 128x64), 512 threads, BK=32
// slots, ring-3 LDS (96 KiB), ONE barrier per slot:
//   { 12 ds_read (bfr then af); stage(P+2) -> slot (P+2)%3 (4 gloads);
//     setprio(1); 32 MFMA; setprio(0); vmcnt(4); s_barrier }
// Counted vmcnt(4): stage(P+2)'s 4 loads may stay in flight; stage(P+1)
// (issued in slot P-1) is proven complete at the slot exit.
// EPI: 0 = f16 out, N=2048: Q (gn<1024) / K (gn>=1024)
//      1 = f16 transposed store Vt[b][n][t]
//      2 = f16 causal energy * 1/sqrt(dk)
//      3 = f32 row-major (PV), nkt = (by+1)*8
// ---------------------------------------------------------------------------
template <int EPI>
DEV void gemm_body(int bx, int by, int z,
                   const _Float16* __restrict__ Ah, const _Float16* __restrict__ Bh,
                   void* __restrict__ out0, void* __restrict__ out2,
                   const int* __restrict__ dkp,
                   int lda, int ldb, size_t aBS, size_t bBS, size_t oBS, int nkt,
                   _Float16* sAb, _Float16* sBb) {
    if (EPI == 3) nkt = (by + 1) * 8;  // causal K extent (BK=32)

    Ah += (size_t)z * aBS;
    Bh += (size_t)z * bBS;

    const float scale = (EPI == 2) ? (1.0f / sqrtf((float)*dkp)) : 1.0f;

    const int tid = threadIdx.x;
    const int wave = tid >> 6, lane = tid & 63;
    const int lr = lane & 15, lk = lane >> 4;
    const int wm = wave >> 2, wn = wave & 3;  // 2 x 4 wave grid
    const int m0 = by * 256, n0 = bx * 256;

    // staging constants (inverse-swizzled global source, linear LDS dest):
    const int so = (lane & 7) ^ (lane >> 3);
    const int strow = 2 * (lane >> 3) + (so >> 2);
    const int stcol = (so & 3) * 8;
    const size_t aoff0 = (size_t)(m0 + (wave * 2 + 0) * 16 + strow) * lda + stcol;
    const size_t aoff1 = (size_t)(m0 + (wave * 2 + 1) * 16 + strow) * lda + stcol;
    const size_t boff0 = (size_t)(n0 + (wave * 2 + 0) * 16 + strow) * ldb + stcol;
    const size_t boff1 = (size_t)(n0 + (wave * 2 + 1) * 16 + strow) * ldb + stcol;
    const int ld0 = (wave * 2 + 0) * 512, ld1 = (wave * 2 + 1) * 512;

    auto stage = [&](int sv, int slot) {
        const int kk = sv * 32;
        _Float16* dA = sAb + slot * SLOT;
        _Float16* dB = sBb + slot * SLOT;
        gload16(Ah + aoff0 + kk, dA + ld0);
        gload16(Ah + aoff1 + kk, dA + ld1);
        gload16(Bh + boff0 + kk, dB + ld0);
        gload16(Bh + boff1 + kk, dB + ld1);
    };

    f32x4 acc[8][4] = {};

    // prologue: slots 0 and 1 in flight; gate slot 0 (allow slot 1's 4 loads)
    stage(0, 0);
    stage(1, 1);
    asm volatile("s_waitcnt vmcnt(4)" ::: "memory");
    __builtin_amdgcn_s_barrier();

    int rP = 0;  // P % 3
    for (int P = 0; P < nkt; ++P) {
        const _Float16* cA = sAb + rP * SLOT;
        const _Float16* cB = sBb + rP * SLOT;
        f16x8 af[8], bfr[4];

        // B frags first so the first MFMA's operands arrive earliest
#pragma unroll
        for (int nj = 0; nj < 4; nj++)
            bfr[nj] = *reinterpret_cast<const f16x8*>(
                &cB[swz_off(wn * 64 + nj * 16 + lr, lk)]);
#pragma unroll
        for (int mi = 0; mi < 8; mi++)
            af[mi] = *reinterpret_cast<const f16x8*>(
                &cA[swz_off(wm * 128 + mi * 16 + lr, lk)]);

        int rs = rP + 2; if (rs >= 3) rs -= 3;
        if (P + 2 < nkt) stage(P + 2, rs);

        __builtin_amdgcn_s_setprio(1);
#pragma unroll
        for (int mi = 0; mi < 8; mi++)
#pragma unroll
            for (int nj = 0; nj < 4; nj++)
                acc[mi][nj] = mfma16(af[mi], bfr[nj], acc[mi][nj]);
        __builtin_amdgcn_s_setprio(0);

        // slot-exit gate: stage(P+1) must be complete (counted; never 0 in
        // steady state).  Skip entirely on the last slot.
        if (P + 2 < nkt) {
            asm volatile("s_waitcnt vmcnt(4)" ::: "memory");
            __builtin_amdgcn_s_barrier();
        } else if (P + 1 < nkt) {
            asm volatile("s_waitcnt vmcnt(0)" ::: "memory");
            __builtin_amdgcn_s_barrier();
        }
        if (++rP == 3) rP = 0;
    }

#pragma unroll
    for (int mi = 0; mi < 8; mi++)
#pragma unroll
        for (int nj = 0; nj < 4; nj++) {
            const int gn = n0 + wn * 64 + nj * 16 + lr;
            if (EPI == 1) {
                const int gm0 = m0 + wm * 128 + mi * 16 + lk * 4;
                const int bb = gm0 >> 11, t = gm0 & (Tc - 1);
                f16x4 pk;
#pragma unroll
                for (int r = 0; r < 4; r++) pk[r] = (_Float16)acc[mi][nj][r];
                *reinterpret_cast<f16x4*>(
                    &((_Float16*)out0)[((size_t)(bb * Hc + gn)) * Tc + t]) = pk;
            } else if (EPI == 0) {
                _Float16* od = (gn < 1024) ? (_Float16*)out0 : (_Float16*)out2;
                const int cc = gn & 1023;
#pragma unroll
                for (int r = 0; r < 4; r++) {
                    const int gm = m0 + wm * 128 + mi * 16 + lk * 4 + r;
                    od[(size_t)gm * Hc + cc] = (_Float16)acc[mi][nj][r];
                }
            } else {
#pragma unroll
                for (int r = 0; r < 4; r++) {
                    const int gm = m0 + wm * 128 + mi * 16 + lk * 4 + r;
                    const float v = acc[mi][nj][r];
                    if (EPI == 2) {
                        const float e = (gn > gm) ? -INFINITY : v * scale;
                        ((unsigned short*)out0)[(size_t)z * oBS + (size_t)gm * Tc + gn] =
                            f16bits(e);
                    } else {
                        ((float*)out0)[(size_t)z * oBS + (size_t)gm * Hc + gn] = v;
                    }
                }
            }
        }
}

// ---------------------------------------------------------------------------
// k_qkv: QK-projection (512 blocks) + V-projection (256 blocks), 32 slots.
// 768 blocks = exactly 3 rounds on 256 CUs.  launch_bounds(512,2): do NOT
// tighten — (512,4) spilled acc to scratch (round 8: 5.8 GB, 9x slowdown).
// ---------------------------------------------------------------------------
__global__ __launch_bounds__(512, 2) void k_qkv(
        const _Float16* __restrict__ Xf, const _Float16* __restrict__ Wall,
        _Float16* __restrict__ Qf, _Float16* __restrict__ Kf,
        _Float16* __restrict__ Vt, const int* __restrict__ dkp) {
    __shared__ _Float16 sA[3][SLOT];  // 48 KiB
    __shared__ _Float16 sB[3][SLOT];  // 48 KiB
    const int i = blockIdx.x;
    if (i < 512) {
        // QK proj: bijective XCD chunking over the (8 x 64) tile grid
        const int w = (i & 7) * 64 + (i >> 3);
        const int by = w >> 3, bx = w & 7;
        gemm_body<0>(bx, by, 0, Xf, Wall, Qf, Kf, dkp,
                     Ec, Ec, 0, 0, 0, 32, sA[0], sB[0]);
    } else {
        const int j = i - 512;  // V proj: (4 x 64) tile grid
        gemm_body<1>(j & 3, j >> 2, 0, Xf, Wall + (size_t)2048 * Ec,
                     Vt, nullptr, dkp, Ec, Ec, 0, 0, 0, 32, sA[0], sB[0]);
    }
}

// ---------------------------------------------------------------------------
// k_energy: 288 causal tiles (36 per batch), single-term f16, 32 slots.
// ---------------------------------------------------------------------------
__global__ __launch_bounds__(512, 2) void k_energy(
        const _Float16* __restrict__ Qf, const _Float16* __restrict__ Kf,
        unsigned short* __restrict__ S, const int* __restrict__ dkp) {
    __shared__ _Float16 sA[3][SLOT];
    __shared__ _Float16 sB[3][SLOT];
    const int i = blockIdx.x;
    const int b = i / 36;
    int t = i - b * 36;
    int by = 0;
    while (t >= by + 1) { t -= by + 1; by++; }  // triangle decode: bx=t <= by
    gemm_body<2>(t, by, b, Qf, Kf, S, nullptr, dkp,
                 Hc, Hc, (size_t)Tc * Hc, (size_t)Tc * Hc, (size_t)Tc * Tc, 32,
                 sA[0], sB[0]);
}

// ---------------------------------------------------------------------------
// k_pv: PV, grid (4, 8, batch); nkt = (by+1)*8 inside body.  P is f16.
// ---------------------------------------------------------------------------
__global__ __launch_bounds__(512, 2) void k_pv(
        const _Float16* __restrict__ S, const _Float16* __restrict__ Vt,
        float* __restrict__ out, const int* __restrict__ dkp) {
    __shared__ _Float16 sA[3][SLOT];
    __shared__ _Float16 sB[3][SLOT];
    gemm_body<3>(blockIdx.x, blockIdx.y, blockIdx.z, S, Vt, out, nullptr, dkp,
                 Tc, Tc, (size_t)Tc * Tc, (size_t)Hc * Tc, (size_t)Tc * Hc, 0,
                 sA[0], sB[0]);
}

// ---------------------------------------------------------------------------
// softmax_w: ONE WAVE per row (4 rows per 256-thread block) — pure __shfl
// reductions, no LDS, no barriers.  f16 logits in, f16 P out (in place).
// Chunks beyond the tile-aligned causal extent skip load/store entirely
// (PV's K-extent is (q/256+1)*256, so those cols are never read).
// ---------------------------------------------------------------------------
__global__ __launch_bounds__(256) void softmax_w(unsigned short* __restrict__ S) {
    const int rid = blockIdx.x * 4 + (threadIdx.x >> 6);  // b*Tc + q
    const int lane = threadIdx.x & 63;
    const int q = rid & (Tc - 1);
    const int limit = ((q >> 8) + 1) << 8;  // tile-aligned causal extent
    unsigned short* row = S + (size_t)rid * Tc;

    float v[4][8];
    bool act[4];
#pragma unroll
    for (int c = 0; c < 4; c++) {
        const int c0 = c * 512 + lane * 8;
        act[c] = c0 < limit;  // limit % 256 == 0, so 8-groups are all-in/out
        if (act[c]) {
            uint4 raw = *reinterpret_cast<const uint4*>(row + c0);
            unsigned u[4] = {raw.x, raw.y, raw.z, raw.w};
#pragma unroll
            for (int p = 0; p < 4; p++) {
                v[c][2 * p]     = f16val((unsigned short)(u[p] & 0xFFFFu));
                v[c][2 * p + 1] = f16val((unsigned short)(u[p] >> 16));
            }
#pragma unroll
            for (int i = 0; i < 8; i++)
                if (c0 + i > q) v[c][i] = -INFINITY;
        } else {
#pragma unroll
            for (int i = 0; i < 8; i++) v[c][i] = -INFINITY;
        }
    }

    float m = -INFINITY;
#pragma unroll
    for (int c = 0; c < 4; c++)
#pragma unroll
        for (int i = 0; i < 8; i++) m = fmaxf(m, v[c][i]);
#pragma unroll
    for (int off = 1; off < 64; off <<= 1) m = fmaxf(m, __shfl_xor(m, off));

    float s = 0.f;
#pragma unroll
    for (int c = 0; c < 4; c++)
#pragma unroll
        for (int i = 0; i < 8; i++) {
            v[c][i] = __expf(v[c][i] - m);  // exp(-inf)=0
            s += v[c][i];
        }
#pragma unroll
    for (int off = 1; off < 64; off <<= 1) s += __shfl_xor(s, off);
    const float inv = 1.0f / s;

#pragma unroll
    for (int c = 0; c < 4; c++) {
        if (!act[c]) continue;
        const int c0 = c * 512 + lane * 8;
        unsigned o[4];
#pragma unroll
        for (int p = 0; p < 4; p++) {
            unsigned short a = f16bits(v[c][2 * p] * inv);
            unsigned short bb = f16bits(v[c][2 * p + 1] * inv);
            o[p] = (unsigned)a | ((unsigned)bb << 16);
        }
        uint4 w; w.x = o[0]; w.y = o[1]; w.z = o[2]; w.w = o[3];
        *reinterpret_cast<uint4*>(row + c0) = w;
    }
}

// ---------------------------------------------------------------------------
extern "C" void kernel_launch(void* const* d_in, const int* in_sizes, int n_in,
                              void* d_out, int out_size, void* d_ws, size_t ws_size,
                              hipStream_t stream) {
    const float* x  = (const float*)d_in[0];
    const float* Wq = (const float*)d_in[1];
    const float* Wk = (const float*)d_in[2];
    const float* Wv = (const float*)d_in[3];
    const int*   dk = (const int*)d_in[4];
    float* out = (float*)d_out;
    char* ws = (char*)d_ws;

    const size_t SZ_XE = (size_t)Mc * Ec * 2;  // 32 MiB (f16 [16384][1024])
    const size_t SZ_W  = (size_t)Ec * Hc * 2;  // 2 MiB

    // Layout: persistent buffers first, prep buffers last so S can alias them.
    size_t o = 0;
    auto nxt = [&](size_t bytes) { void* p = ws + o; o += bytes; return p; };
    _Float16* Qf   = (_Float16*)nxt(SZ_XE);
    _Float16* Kf   = (_Float16*)nxt(SZ_XE);
    _Float16* Vt   = (_Float16*)nxt(SZ_XE);
    _Float16* Xf   = (_Float16*)nxt(SZ_XE);
    _Float16* Wall = (_Float16*)nxt(3 * SZ_W);  // [3072][1024] = Wq|Wk|Wv, transposed
    // S: all-batch f16 [8][2048][2048] = 64 MiB, aliases Xf+Wall+beyond
    // (Xf and Wall are dead once k_qkv completes; k_energy is stream-ordered).
    unsigned short* S = (unsigned short*)Xf;
    (void)ws_size; (void)in_sizes; (void)n_in; (void)out_size;

    // merged prep: x->f16 (16384 blocks) + W transpose (3072 blocks)
    k_prep<<<19456, 256, 0, stream>>>(x, Wq, Wk, Wv, Xf, Wall);

    // Q, K, V projections: single-term f16, K=1024 (round-13 config)
    k_qkv<<<768, 512, 0, stream>>>(Xf, Wall, Qf, Kf, Vt, dk);

    // energy: 288 causal tiles, f16 logits (round-13 config)
    k_energy<<<288, 512, 0, stream>>>(Qf, Kf, (unsigned short*)S, dk);

    // softmax: one wave per row, 4 rows/block
    softmax_w<<<Bc * Tc / 4, 256, 0, stream>>>((unsigned short*)S);

    // PV: nkt=(by+1)*8 per tile (P beyond causal edge is 0)
    k_pv<<<dim3(4, 8, Bc), 512, 0, stream>>>((const _Float16*)S, Vt, out, dk);
}